// Round 9
// baseline (162.902 us; speedup 1.0000x reference)
//
#include <hip/hip_runtime.h>
#include <hip/hip_bf16.h>

#define B_DIM 8
#define T_DIM 2048
#define C_DIM 1024
#define H_DIM 64
#define BT (B_DIM * T_DIM)

typedef __attribute__((ext_vector_type(8))) short bf16x8;
typedef __attribute__((ext_vector_type(4))) float f32x4;

__device__ __forceinline__ ushort f2bf(float f) {
    __hip_bfloat16 h = __float2bfloat16(f);
    return *reinterpret_cast<ushort*>(&h);
}
__device__ __forceinline__ unsigned int packbf(float a, float b) {
    return (unsigned int)f2bf(a) | ((unsigned int)f2bf(b) << 16);
}

// ---------------------------------------------------------------------------
// Wt[n][k] = W(sel)[k][n&63]; n<64: Wk, n<128: Wq (pre-scaled by 0.125*log2e
// so attention runs in exp2 domain), else Wv. bf16. grid=192 x 256 thr.
// ---------------------------------------------------------------------------
__global__ __launch_bounds__(256) void wt_convert_kernel(
    const float* __restrict__ Wk, const float* __restrict__ Wq,
    const float* __restrict__ Wv, ushort* __restrict__ wt)
{
    const int n = blockIdx.x;
    const float* src = (n < 64) ? Wk : (n < 128) ? Wq : Wv;
    const float scale = (n >= 64 && n < 128) ? 0.125f * 1.4426950408889634f : 1.0f;
    const int col = n & 63;
    for (int k = threadIdx.x; k < C_DIM; k += 256)
        wt[(size_t)n * C_DIM + k] = f2bf(src[(size_t)k * H_DIM + col] * scale);
}

// ---------------------------------------------------------------------------
// QKV GEMM v5: M=32/block, 512 blocks x 512 thr (8 waves). Wave = (kh, nh):
// kh splits K in half (512 each) -> 16 waves/CU (2x v4); nh keeps the v4
// 3-n-tile split. W frags global->VGPR, register-double-buffered (each W
// element still read once per block). x staged f32->bf16 into per-kh
// double-buffered LDS; 8 barriers (v4: 16). kh=1 partial accs merge into
// kh=0 via pad-25 LDS (conflict-free), then v4 epilogue on kh=0 waves.
// ---------------------------------------------------------------------------
__global__ __launch_bounds__(512, 4) void qkv_gemm_kernel(
    const float* __restrict__ x, const ushort* __restrict__ wt,
    ushort* __restrict__ kb, ushort* __restrict__ qb, ushort* __restrict__ vt)
{
    __shared__ ushort Xf[2][2][4 * 64 * 8];  // 16 KB [buf][kh][mf*2+ks][lane][8]
    __shared__ float  Ls[256 * 25];          // 25.6 KB kh=1 partials, pad-25
    const int tid = threadIdx.x;
    const int wave = tid >> 6, lane = tid & 63;
    const int kh = wave >> 2, nh = wave & 3;
    const int col = lane & 15, quad = lane >> 4;
    const int r0 = blockIdx.x * 32;
    const int kbase = kh * 512;

    f32x4 acc[2][3];
    #pragma unroll
    for (int m = 0; m < 2; ++m)
        #pragma unroll
        for (int j = 0; j < 3; ++j) acc[m][j] = (f32x4){0.f, 0.f, 0.f, 0.f};

    // x staging: wave owns region nh (mf=nh>>1, ks=nh&1) of its kh half
    const float* xsrc = x + (size_t)(r0 + (nh >> 1) * 16 + col) * C_DIM
                          + kbase + (nh & 1) * 32 + quad * 8;
    ushort* xdst[2] = {&Xf[0][kh][(nh * 64 + lane) * 8],
                       &Xf[1][kh][(nh * 64 + lane) * 8]};

    // W fragments for THIS wave: n-tiles nh*3+j, this kh half
    const ushort* wsrc[3][2];
    #pragma unroll
    for (int j = 0; j < 3; ++j)
        #pragma unroll
        for (int ks = 0; ks < 2; ++ks)
            wsrc[j][ks] = wt + (size_t)((nh * 3 + j) * 16 + col) * C_DIM
                             + kbase + ks * 32 + quad * 8;

    // ---- prologue: slab 0 ----
    {
        const float4 f0 = *(const float4*)(xsrc);
        const float4 f1 = *(const float4*)(xsrc + 4);
        uint4 u;
        u.x = packbf(f0.x, f0.y); u.y = packbf(f0.z, f0.w);
        u.z = packbf(f1.x, f1.y); u.w = packbf(f1.z, f1.w);
        *(uint4*)xdst[0] = u;
    }
    bf16x8 wcur[3][2];
    #pragma unroll
    for (int j = 0; j < 3; ++j)
        #pragma unroll
        for (int ks = 0; ks < 2; ++ks)
            wcur[j][ks] = *(const bf16x8*)(wsrc[j][ks]);
    __syncthreads();

    for (int i = 0; i < 8; ++i) {
        const int b = i & 1;
        bf16x8 wnxt[3][2];
        float4 nf0, nf1;
        if (i < 7) {
            const int k1 = (i + 1) * 64;
            #pragma unroll
            for (int j = 0; j < 3; ++j)
                #pragma unroll
                for (int ks = 0; ks < 2; ++ks)
                    wnxt[j][ks] = *(const bf16x8*)(wsrc[j][ks] + k1);
            nf0 = *(const float4*)(xsrc + k1);
            nf1 = *(const float4*)(xsrc + k1 + 4);
        }
        // ---- compute slab i ----
        bf16x8 a[2][2];
        #pragma unroll
        for (int mf = 0; mf < 2; ++mf)
            #pragma unroll
            for (int ks = 0; ks < 2; ++ks)
                a[mf][ks] = *(const bf16x8*)&Xf[b][kh][((mf * 2 + ks) * 64 + lane) * 8];
        #pragma unroll
        for (int ks = 0; ks < 2; ++ks)
            #pragma unroll
            for (int j = 0; j < 3; ++j) {
                acc[0][j] = __builtin_amdgcn_mfma_f32_16x16x32_bf16(a[0][ks], wcur[j][ks], acc[0][j], 0, 0, 0);
                acc[1][j] = __builtin_amdgcn_mfma_f32_16x16x32_bf16(a[1][ks], wcur[j][ks], acc[1][j], 0, 0, 0);
            }
        if (i < 7) {
            #pragma unroll
            for (int j = 0; j < 3; ++j)
                #pragma unroll
                for (int ks = 0; ks < 2; ++ks)
                    wcur[j][ks] = wnxt[j][ks];
            uint4 u;
            u.x = packbf(nf0.x, nf0.y); u.y = packbf(nf0.z, nf0.w);
            u.z = packbf(nf1.x, nf1.y); u.w = packbf(nf1.z, nf1.w);
            *(uint4*)xdst[b ^ 1] = u;
        }
        __syncthreads();
    }

    // ---- k-halves merge: kh=1 -> LDS, kh=0 adds ----
    if (kh == 1) {
        float* dst = &Ls[(tid & 255) * 25];
        #pragma unroll
        for (int mf = 0; mf < 2; ++mf)
            #pragma unroll
            for (int j = 0; j < 3; ++j)
                #pragma unroll
                for (int r = 0; r < 4; ++r)
                    dst[(mf * 3 + j) * 4 + r] = acc[mf][j][r];
    }
    __syncthreads();
    if (kh == 0) {
        const float* srcl = &Ls[tid * 25];
        #pragma unroll
        for (int mf = 0; mf < 2; ++mf)
            #pragma unroll
            for (int j = 0; j < 3; ++j)
                #pragma unroll
                for (int r = 0; r < 4; ++r)
                    acc[mf][j][r] += srcl[(mf * 3 + j) * 4 + r];

        // epilogue: C layout col=lane&15, row=quad*4+reg (+ mf*16)
        #pragma unroll
        for (int j = 0; j < 3; ++j) {
            const int nt = nh * 3 + j;
            #pragma unroll
            for (int mf = 0; mf < 2; ++mf) {
                const int rbase = r0 + mf * 16 + quad * 4;
                if (nt < 4) {
                    const int n = nt * 16 + col;
                    #pragma unroll
                    for (int r = 0; r < 4; ++r)
                        kb[(size_t)(rbase + r) * H_DIM + n] = f2bf(acc[mf][j][r]);
                } else if (nt < 8) {
                    const int n = nt * 16 + col - 64;
                    #pragma unroll
                    for (int r = 0; r < 4; ++r)
                        qb[(size_t)(rbase + r) * H_DIM + n] = f2bf(acc[mf][j][r]);
                } else {
                    const int h = nt * 16 + col - 128;
                    const int vbatch = rbase >> 11, vrow = rbase & (T_DIM - 1);
                    ushort u4[4] = {f2bf(acc[mf][j][0]), f2bf(acc[mf][j][1]),
                                    f2bf(acc[mf][j][2]), f2bf(acc[mf][j][3])};
                    unsigned long long uu; __builtin_memcpy(&uu, u4, 8);
                    *(unsigned long long*)(vt + ((size_t)vbatch * H_DIM + h) * T_DIM + vrow) = uu;
                }
            }
        }
    }
}

// ---------------------------------------------------------------------------
// MFMA flash attention v3: S^T formulation + TWO interleaved online-softmax
// states per wave (tiles t==w and t==w+4 mod 8) for ILP -- B's S-MFMAs issue
// under A's softmax VALU chain. grid = 8 batches x 128 q-tiles (4 blocks/CU,
// 16 waves/CU). States use disjoint Ps regions; A/B merged in-register
// (-inf guarded), then the 4 wave partials merge via LDS (one barrier).
// ---------------------------------------------------------------------------
__global__ __launch_bounds__(256, 4) void attn_kernel(
    const ushort* __restrict__ kb, const ushort* __restrict__ qb,
    const ushort* __restrict__ vt, float* __restrict__ out)
{
    __shared__ unsigned int Ps[8][16 * 34];  // per-wave-state P^T, stride 34
    __shared__ float Om[4][64][17];          // wave partial O^T [h][q]
    __shared__ float Mm[4][16], Lm[4][16];

    const int tid = threadIdx.x;
    const int wave = tid >> 6, lane = tid & 63;
    const int col = lane & 15, quad = lane >> 4;  // col = q
    const int batch = blockIdx.x & 7;
    const int qtile = 127 - (blockIdx.x >> 3);
    const int q0 = qtile * 16;

    const ushort* kbase = kb + (size_t)batch * T_DIM * H_DIM;
    const ushort* vbase = vt + (size_t)batch * H_DIM * T_DIM;

    const size_t qoff = (size_t)(batch * T_DIM + q0 + col) * H_DIM + quad * 8;
    const bf16x8 bq0 = *(const bf16x8*)(qb + qoff);
    const bf16x8 bq1 = *(const bf16x8*)(qb + qoff + 32);

    float mA = -INFINITY, lA = 0.f, mB = -INFINITY, lB = 0.f;
    f32x4 oA[4], oB[4];
    #pragma unroll
    for (int i = 0; i < 4; ++i) {
        oA[i] = (f32x4){0.f, 0.f, 0.f, 0.f};
        oB[i] = (f32x4){0.f, 0.f, 0.f, 0.f};
    }

    const int ntiles = (q0 + 16 + 63) >> 6;

    auto qk_tile = [&](int kb0, f32x4* s) {
        #pragma unroll
        for (int mt = 0; mt < 4; ++mt) s[mt] = (f32x4){0.f, 0.f, 0.f, 0.f};
        #pragma unroll
        for (int ks = 0; ks < 2; ++ks) {
            const bf16x8 bq = ks ? bq1 : bq0;
            #pragma unroll
            for (int mt = 0; mt < 4; ++mt) {
                const bf16x8 ak = *(const bf16x8*)
                    (kbase + (size_t)(kb0 + mt * 16 + col) * H_DIM + ks * 32 + quad * 8);
                s[mt] = __builtin_amdgcn_mfma_f32_16x16x32_bf16(ak, bq, s[mt], 0, 0, 0);
            }
        }
        if (kb0 + 63 > q0) {   // causal mask: key = kb0+mt*16+quad*4+reg, q = q0+col
            const int kq = kb0 + quad * 4 - q0 - col;
            #pragma unroll
            for (int mt = 0; mt < 4; ++mt)
                #pragma unroll
                for (int reg = 0; reg < 4; ++reg)
                    if (kq + mt * 16 + reg > 0) s[mt][reg] = -INFINITY;
        }
    };

    auto sm_pv = [&](int kb0, f32x4* s, float& m_, float& l_, f32x4* o_,
                     unsigned int* psw) {
        float mr = -INFINITY;
        #pragma unroll
        for (int mt = 0; mt < 4; ++mt)
            #pragma unroll
            for (int reg = 0; reg < 4; ++reg) mr = fmaxf(mr, s[mt][reg]);
        mr = fmaxf(mr, __shfl_xor(mr, 16));
        mr = fmaxf(mr, __shfl_xor(mr, 32));
        const float mn = fmaxf(m_, mr);
        const float corr = exp2f(m_ - mn);   // 0 on first tile
        float sum = 0.f;
        #pragma unroll
        for (int mt = 0; mt < 4; ++mt)
            #pragma unroll
            for (int reg = 0; reg < 4; ++reg) {
                const float pv = exp2f(s[mt][reg] - mn);
                s[mt][reg] = pv;
                sum += pv;
            }
        sum += __shfl_xor(sum, 16);
        sum += __shfl_xor(sum, 32);
        l_ = l_ * corr + sum;
        m_ = mn;
        #pragma unroll
        for (int ht = 0; ht < 4; ++ht) o_[ht] *= corr;
        #pragma unroll
        for (int mt = 0; mt < 4; ++mt) {
            uint2 w2;
            w2.x = packbf(s[mt][0], s[mt][1]);
            w2.y = packbf(s[mt][2], s[mt][3]);
            *(uint2*)&psw[col * 34 + mt * 8 + quad * 2] = w2;
        }
        #pragma unroll
        for (int ks2 = 0; ks2 < 2; ++ks2) {
            const uint2 ra = *(const uint2*)&psw[col * 34 + ks2 * 16 + quad * 4];
            const uint2 rb = *(const uint2*)&psw[col * 34 + ks2 * 16 + quad * 4 + 2];
            unsigned int ub[4] = {ra.x, ra.y, rb.x, rb.y};
            bf16x8 bp; __builtin_memcpy(&bp, ub, 16);
            #pragma unroll
            for (int ht = 0; ht < 4; ++ht) {
                const bf16x8 av = *(const bf16x8*)
                    (vbase + (size_t)(ht * 16 + col) * T_DIM + kb0 + ks2 * 32 + quad * 8);
                o_[ht] = __builtin_amdgcn_mfma_f32_16x16x32_bf16(av, bp, o_[ht], 0, 0, 0);
            }
        }
    };

    for (int t = wave; t < ntiles; t += 8) {
        const int t2 = t + 4;
        const bool hasB = t2 < ntiles;     // wave-uniform
        f32x4 sA[4], sB[4];
        qk_tile(t * 64, sA);
        if (hasB) qk_tile(t2 * 64, sB);    // independent MFMAs under A's softmax
        sm_pv(t * 64, sA, mA, lA, oA, &Ps[wave][0]);
        if (hasB) sm_pv(t2 * 64, sB, mB, lB, oB, &Ps[wave + 4][0]);
    }

    // ---- in-register A/B merge (guard -inf for idle states) ----
    const float M = fmaxf(mA, mB);
    const float eA = (mA == -INFINITY) ? 0.f : exp2f(mA - M);
    const float eB = (mB == -INFINITY) ? 0.f : exp2f(mB - M);
    const float L = lA * eA + lB * eB;
    #pragma unroll
    for (int ht = 0; ht < 4; ++ht)
        #pragma unroll
        for (int reg = 0; reg < 4; ++reg)
            Om[wave][ht * 16 + quad * 4 + reg][col] = oA[ht][reg] * eA + oB[ht][reg] * eB;
    if (lane < 16) { Mm[wave][lane] = M; Lm[wave][lane] = L; }
    __syncthreads();
    // ---- merge 4 wave partials; idle waves (m=-inf,l=0,o=0) contribute 0 ----
    {
        const int q = tid >> 4, hb = tid & 15;
        const float Mb = fmaxf(fmaxf(Mm[0][q], Mm[1][q]), fmaxf(Mm[2][q], Mm[3][q]));
        const float a0 = exp2f(Mm[0][q] - Mb), a1 = exp2f(Mm[1][q] - Mb);
        const float a2 = exp2f(Mm[2][q] - Mb), a3 = exp2f(Mm[3][q] - Mb);
        const float Lb = Lm[0][q] * a0 + Lm[1][q] * a1 + Lm[2][q] * a2 + Lm[3][q] * a3;
        const float rL = 1.0f / Lb;
        float* orow = out + (size_t)(batch * T_DIM + q0 + q) * H_DIM;
        #pragma unroll
        for (int i = 0; i < 4; ++i) {
            const int h = hb + 16 * i;
            orow[h] = (Om[0][h][q] * a0 + Om[1][h][q] * a1 +
                       Om[2][h][q] * a2 + Om[3][h][q] * a3) * rL;
        }
    }
}

extern "C" void kernel_launch(void* const* d_in, const int* in_sizes, int n_in,
                              void* d_out, int out_size, void* d_ws, size_t ws_size,
                              hipStream_t stream)
{
    const float* x  = (const float*)d_in[0];
    const float* Wk = (const float*)d_in[1];
    const float* Wq = (const float*)d_in[2];
    const float* Wv = (const float*)d_in[3];

    ushort* kbuf = (ushort*)d_ws;                       // [BT][64] bf16
    ushort* qbuf = kbuf + (size_t)BT * H_DIM;           // [BT][64] bf16 (pre-scaled)
    ushort* vtb  = qbuf + (size_t)BT * H_DIM;           // V^T [8][64][2048] bf16
    ushort* wt   = vtb  + (size_t)BT * H_DIM;           // [192][1024] bf16

    wt_convert_kernel<<<192, 256, 0, stream>>>(Wk, Wq, Wv, wt);
    qkv_gemm_kernel<<<BT / 32, 512, 0, stream>>>(x, wt, kbuf, qbuf, vtb);
    attn_kernel<<<B_DIM * 128, 256, 0, stream>>>(kbuf, qbuf, vtb, (float*)d_out);
}